// Round 2
// baseline (246.961 us; speedup 1.0000x reference)
//
#include <hip/hip_runtime.h>

#define D 2048
#define RANK 16

// ==================== Kernel 1: partial t = h · B^T (per d-half) ============
// grid = (n_rows/8)*2 blocks, 256 threads (4 waves).
// block: rowblk = blockIdx>>1 (8 rows), half = blockIdx&1 (d-half of 1024).
// wave rg = tid>>6 owns ranks rg*4..rg*4+3; lane dg owns d = half*1024 + c*256 + dg*4.
// No LDS, no barriers: wave-level shfl reduce, lane0 stores partials to ws.
__global__ __launch_bounds__(256, 3)
void lora_phase1(const float* __restrict__ h, const float* __restrict__ B,
                 float* __restrict__ ws, int n_rows) {
    const int tid  = threadIdx.x;
    const int lane = tid & 63;
    const int rg   = tid >> 6;           // 0..3 rank-quad
    const int half = blockIdx.x & 1;     // d-half
    const long row0 = (long)(blockIdx.x >> 1) * 8;
    const int dbase = half * 1024 + lane * 4;

    // B fragment: 64 floats/thread, loaded once, reused for 8 rows
    float4 Bf[4][4];
#pragma unroll
    for (int r = 0; r < 4; ++r)
#pragma unroll
        for (int c = 0; c < 4; ++c)
            Bf[r][c] = *reinterpret_cast<const float4*>(
                &B[(rg * 4 + r) * D + dbase + c * 256]);

    float acc[8][4];
#pragma unroll
    for (int i = 0; i < 8; ++i)
#pragma unroll
        for (int r = 0; r < 4; ++r) acc[i][r] = 0.f;

#pragma unroll
    for (int i = 0; i < 8; ++i) {
        float4 hv[4];
#pragma unroll
        for (int c = 0; c < 4; ++c)
            hv[c] = *reinterpret_cast<const float4*>(
                &h[(row0 + i) * D + dbase + c * 256]);
#pragma unroll
        for (int r = 0; r < 4; ++r)
#pragma unroll
            for (int c = 0; c < 4; ++c)
                acc[i][r] += hv[c].x * Bf[r][c].x + hv[c].y * Bf[r][c].y +
                             hv[c].z * Bf[r][c].z + hv[c].w * Bf[r][c].w;
    }

    // wave-level butterfly reduce: 32 independent chains, 6 steps
#pragma unroll
    for (int m = 1; m < 64; m <<= 1)
#pragma unroll
        for (int i = 0; i < 8; ++i)
#pragma unroll
            for (int r = 0; r < 4; ++r)
                acc[i][r] += __shfl_xor(acc[i][r], m, 64);

    if (lane == 0) {
#pragma unroll
        for (int i = 0; i < 8; ++i) {
            *reinterpret_cast<float4*>(
                &ws[((long)half * n_rows + row0 + i) * RANK + rg * 4]) =
                make_float4(acc[i][0], acc[i][1], acc[i][2], acc[i][3]);
        }
    }
}

// ==================== Kernel 2: out = t · A^T ===============================
// grid = n_rows/16 blocks, 512 threads. Thread owns out cols e = tid*4..+3,
// A slice (64 floats) in regs, loops 16 rows. t[row] loads are wave-uniform
// broadcasts (L1-hit). Streaming float4 stores, write-bound.
__global__ __launch_bounds__(512, 4)
void lora_phase2(const float* __restrict__ ws, const float* __restrict__ A,
                 float* __restrict__ out, int n_rows) {
    const int tid = threadIdx.x;
    const int e0  = tid * 4;
    const long row0 = (long)blockIdx.x * 16;

    float4 Af[4][4];
#pragma unroll
    for (int j = 0; j < 4; ++j)
#pragma unroll
        for (int q = 0; q < 4; ++q)
            Af[j][q] = *reinterpret_cast<const float4*>(
                &A[(e0 + j) * RANK + q * 4]);

    for (int i = 0; i < 16; ++i) {
        const long row = row0 + i;
        float4 tq[4];
#pragma unroll
        for (int q = 0; q < 4; ++q) {
            float4 p0 = *reinterpret_cast<const float4*>(
                &ws[row * RANK + q * 4]);
            float4 p1 = *reinterpret_cast<const float4*>(
                &ws[((long)n_rows + row) * RANK + q * 4]);
            tq[q] = make_float4(p0.x + p1.x, p0.y + p1.y, p0.z + p1.z,
                                p0.w + p1.w);
        }
        float res[4];
#pragma unroll
        for (int j = 0; j < 4; ++j) {
            float v = 0.f;
#pragma unroll
            for (int q = 0; q < 4; ++q)
                v += tq[q].x * Af[j][q].x + tq[q].y * Af[j][q].y +
                     tq[q].z * Af[j][q].z + tq[q].w * Af[j][q].w;
            res[j] = v;
        }
        *reinterpret_cast<float4*>(&out[row * D + e0]) =
            make_float4(res[0], res[1], res[2], res[3]);
    }
}

// ==================== Fallback: round-1 fused kernel (ws too small) =========
#define ROWS_PER_BLOCK 32
#define NTHREADS 512

__global__ __launch_bounds__(NTHREADS, 2)
void lora_fused_kernel(const float* __restrict__ h,
                       const float* __restrict__ A,
                       const float* __restrict__ B,
                       float* __restrict__ out) {
    const int tid  = threadIdx.x;
    const int dg   = tid & 127;
    const int rg   = tid >> 7;
    const int wave = tid >> 6;
    const int lane = tid & 63;
    const long row0 = (long)blockIdx.x * ROWS_PER_BLOCK;

    float4 Bf[4][4];
#pragma unroll
    for (int r = 0; r < 4; ++r)
#pragma unroll
        for (int c = 0; c < 4; ++c)
            Bf[r][c] = *reinterpret_cast<const float4*>(
                &B[(rg * 4 + r) * D + c * 512 + dg * 4]);

    float4 Af[4][4];
#pragma unroll
    for (int j = 0; j < 4; ++j)
#pragma unroll
        for (int q = 0; q < 4; ++q)
            Af[j][q] = *reinterpret_cast<const float4*>(
                &A[(tid * 4 + j) * RANK + q * 4]);

    __shared__ float4 lds_part[2][8];
    const int dbase = dg * 4;

    float4 hn[4];
#pragma unroll
    for (int c = 0; c < 4; ++c)
        hn[c] = *reinterpret_cast<const float4*>(&h[row0 * D + c * 512 + dbase]);
    {
        float acc[4] = {0.f, 0.f, 0.f, 0.f};
#pragma unroll
        for (int r = 0; r < 4; ++r)
#pragma unroll
            for (int c = 0; c < 4; ++c)
                acc[r] += hn[c].x * Bf[r][c].x + hn[c].y * Bf[r][c].y +
                          hn[c].z * Bf[r][c].z + hn[c].w * Bf[r][c].w;
#pragma unroll
        for (int m = 1; m < 64; m <<= 1)
#pragma unroll
            for (int r = 0; r < 4; ++r)
                acc[r] += __shfl_xor(acc[r], m, 64);
        if (lane == 0)
            lds_part[0][wave] = make_float4(acc[0], acc[1], acc[2], acc[3]);
    }
#pragma unroll
    for (int c = 0; c < 4; ++c)
        hn[c] = *reinterpret_cast<const float4*>(
            &h[(row0 + 1) * D + c * 512 + dbase]);
    __syncthreads();

    for (int i = 0; i < ROWS_PER_BLOCK; ++i) {
        const int buf = i & 1;
        float4 hn2[4];
        if (i + 2 < ROWS_PER_BLOCK) {
#pragma unroll
            for (int c = 0; c < 4; ++c)
                hn2[c] = *reinterpret_cast<const float4*>(
                    &h[(row0 + i + 2) * D + c * 512 + dbase]);
        }
        if (i + 1 < ROWS_PER_BLOCK) {
            float acc[4] = {0.f, 0.f, 0.f, 0.f};
#pragma unroll
            for (int r = 0; r < 4; ++r)
#pragma unroll
                for (int c = 0; c < 4; ++c)
                    acc[r] += hn[c].x * Bf[r][c].x + hn[c].y * Bf[r][c].y +
                              hn[c].z * Bf[r][c].z + hn[c].w * Bf[r][c].w;
#pragma unroll
            for (int m = 1; m < 64; m <<= 1)
#pragma unroll
                for (int r = 0; r < 4; ++r)
                    acc[r] += __shfl_xor(acc[r], m, 64);
            if (lane == 0)
                lds_part[buf ^ 1][wave] =
                    make_float4(acc[0], acc[1], acc[2], acc[3]);
        }
        {
            float4 tq[4];
#pragma unroll
            for (int q = 0; q < 4; ++q) {
                float4 p0 = lds_part[buf][2 * q];
                float4 p1 = lds_part[buf][2 * q + 1];
                tq[q] = make_float4(p0.x + p1.x, p0.y + p1.y, p0.z + p1.z,
                                    p0.w + p1.w);
            }
            float res[4];
#pragma unroll
            for (int j = 0; j < 4; ++j) {
                float v = 0.f;
#pragma unroll
                for (int q = 0; q < 4; ++q)
                    v += tq[q].x * Af[j][q].x + tq[q].y * Af[j][q].y +
                         tq[q].z * Af[j][q].z + tq[q].w * Af[j][q].w;
                res[j] = v;
            }
            *reinterpret_cast<float4*>(&out[(row0 + i) * D + tid * 4]) =
                make_float4(res[0], res[1], res[2], res[3]);
        }
        __syncthreads();
#pragma unroll
        for (int c = 0; c < 4; ++c) hn[c] = hn2[c];
    }
}

extern "C" void kernel_launch(void* const* d_in, const int* in_sizes, int n_in,
                              void* d_out, int out_size, void* d_ws,
                              size_t ws_size, hipStream_t stream) {
    const float* h = (const float*)d_in[0];
    const float* A = (const float*)d_in[1];
    const float* B = (const float*)d_in[2];
    float* out = (float*)d_out;

    const int n_rows = in_sizes[0] / D;  // 16384
    const size_t ws_needed = (size_t)2 * n_rows * RANK * sizeof(float);

    if (ws_size >= ws_needed) {
        float* ws = (float*)d_ws;
        const int blocks1 = (n_rows / 8) * 2;   // 4096
        hipLaunchKernelGGL(lora_phase1, dim3(blocks1), dim3(256), 0, stream,
                           h, B, ws, n_rows);
        const int blocks2 = n_rows / 16;        // 1024
        hipLaunchKernelGGL(lora_phase2, dim3(blocks2), dim3(512), 0, stream,
                           ws, A, out, n_rows);
    } else {
        const int blocks = n_rows / ROWS_PER_BLOCK;
        hipLaunchKernelGGL(lora_fused_kernel, dim3(blocks), dim3(NTHREADS), 0,
                           stream, h, A, B, out);
    }
}

// Round 3
// 79.250 us; speedup vs baseline: 3.1162x; 3.1162x over previous
//
#include <hip/hip_runtime.h>

typedef float f4 __attribute__((ext_vector_type(4)));

#define D 2048
#define RANK 16
#define ROWS 32                 // rows per block
#define G 2                     // rows per group (per barrier cycle)
#define NGROUPS (ROWS / G)      // 16
#define NT 512

__device__ __forceinline__ float dot4(f4 a, f4 b) {
    return a.x * b.x + a.y * b.y + a.z * b.z + a.w * b.w;
}

// Fused LoRA: out = h @ (A@B)^T, factored through rank-16.
// 512 threads = 8 waves. Wave w: rank-quad rg = w>>1, d-half = w&1.
// Thread (dg = tid&127, rg): d-slice {dg*4 + c*512}, c=0..3.
// Bf (64 floats) + Af (64 floats) REGISTER-RESIDENT for the whole block
// (launch_bounds(512,1) gives the 256-VGPR budget; round-1's (512,2)
// forced the compiler to re-load them every row = ~2 GB of L2 traffic).
__global__ __launch_bounds__(NT, 1)
void lora_fused2(const float* __restrict__ h, const float* __restrict__ A,
                 const float* __restrict__ B, float* __restrict__ out) {
    const int tid  = threadIdx.x;
    const int dg   = tid & 127;
    const int rg   = tid >> 7;
    const int wave = tid >> 6;
    const int lane = tid & 63;
    const long row0 = (long)blockIdx.x * ROWS;
    const int dbase = dg * 4;

    // ---- resident B fragment: Bf[r][c] = B[(rg*4+r)*D + c*512 + dbase] ----
    f4 Bf[4][4];
#pragma unroll
    for (int r = 0; r < 4; ++r)
#pragma unroll
        for (int c = 0; c < 4; ++c)
            Bf[r][c] = *reinterpret_cast<const f4*>(
                &B[(rg * 4 + r) * D + c * 512 + dbase]);

    // ---- resident A fragment: Af[j][q] = A[(tid*4+j)*RANK + q*4] ----
    f4 Af[4][4];
#pragma unroll
    for (int j = 0; j < 4; ++j)
#pragma unroll
        for (int q = 0; q < 4; ++q)
            Af[j][q] = *reinterpret_cast<const f4*>(
                &A[(tid * 4 + j) * RANK + q * 4]);

    // per-wave rank partials, double-buffered: [buf][row-in-group][wave]
    __shared__ f4 part[2][G][8];

    // phase1: rank-partials for G rows -> part[dst]
    auto phase1 = [&](const f4 (&hh)[G][4], int dst) {
        float acc[G][4];
#pragma unroll
        for (int g = 0; g < G; ++g)
#pragma unroll
            for (int r = 0; r < 4; ++r) acc[g][r] = 0.f;
#pragma unroll
        for (int g = 0; g < G; ++g)
#pragma unroll
            for (int r = 0; r < 4; ++r)
#pragma unroll
                for (int c = 0; c < 4; ++c)
                    acc[g][r] += dot4(hh[g][c], Bf[r][c]);
        // butterfly reduce across the wave: G*4 = 8 independent chains
#pragma unroll
        for (int m = 1; m < 64; m <<= 1)
#pragma unroll
            for (int g = 0; g < G; ++g)
#pragma unroll
                for (int r = 0; r < 4; ++r)
                    acc[g][r] += __shfl_xor(acc[g][r], m, 64);
        if (lane == 0) {
#pragma unroll
            for (int g = 0; g < G; ++g) {
                f4 v;
                v.x = acc[g][0]; v.y = acc[g][1];
                v.z = acc[g][2]; v.w = acc[g][3];
                part[dst][g][wave] = v;
            }
        }
    };

    // phase2: out rows of group grp from part[buf]
    auto phase2 = [&](int buf, int grp) {
#pragma unroll
        for (int g = 0; g < G; ++g) {
            f4 tq[4];
#pragma unroll
            for (int q = 0; q < 4; ++q)
                tq[q] = part[buf][g][2 * q] + part[buf][g][2 * q + 1];
            f4 res;
            res.x = res.y = res.z = res.w = 0.f;
#pragma unroll
            for (int q = 0; q < 4; ++q) {
                res.x += dot4(tq[q], Af[0][q]);
                res.y += dot4(tq[q], Af[1][q]);
                res.z += dot4(tq[q], Af[2][q]);
                res.w += dot4(tq[q], Af[3][q]);
            }
            // nontemporal: keep the 128 MB write stream from evicting
            // h/A/B out of L2/L3
            __builtin_nontemporal_store(
                res, reinterpret_cast<f4*>(
                         &out[(row0 + (long)grp * G + g) * D + tid * 4]));
        }
    };

    f4 hg[G][4];  // h for the NEXT group to run phase1 on

    // ---- prologue: phase1(group 0), prefetch group 1 ----
#pragma unroll
    for (int g = 0; g < G; ++g)
#pragma unroll
        for (int c = 0; c < 4; ++c)
            hg[g][c] = *reinterpret_cast<const f4*>(
                &h[(row0 + g) * D + c * 512 + dbase]);
    phase1(hg, 0);
#pragma unroll
    for (int g = 0; g < G; ++g)
#pragma unroll
        for (int c = 0; c < 4; ++c)
            hg[g][c] = *reinterpret_cast<const f4*>(
                &h[(row0 + G + g) * D + c * 512 + dbase]);
    __syncthreads();

    // ---- main loop: prefetch(grp+2) || phase1(grp+1) || phase2(grp) ----
#pragma unroll 2
    for (int grp = 0; grp < NGROUPS; ++grp) {
        const int buf = grp & 1;

        f4 hn[G][4];
        if (grp + 2 < NGROUPS) {
#pragma unroll
            for (int g = 0; g < G; ++g)
#pragma unroll
                for (int c = 0; c < 4; ++c)
                    hn[g][c] = *reinterpret_cast<const f4*>(
                        &h[(row0 + (long)(grp + 2) * G + g) * D + c * 512 +
                           dbase]);
        }

        if (grp + 1 < NGROUPS) phase1(hg, buf ^ 1);

        phase2(buf, grp);

        __syncthreads();
#pragma unroll
        for (int g = 0; g < G; ++g)
#pragma unroll
            for (int c = 0; c < 4; ++c) hg[g][c] = hn[g][c];
    }
}

extern "C" void kernel_launch(void* const* d_in, const int* in_sizes, int n_in,
                              void* d_out, int out_size, void* d_ws,
                              size_t ws_size, hipStream_t stream) {
    const float* h = (const float*)d_in[0];
    const float* A = (const float*)d_in[1];
    const float* B = (const float*)d_in[2];
    float* out = (float*)d_out;

    const int n_rows = in_sizes[0] / D;   // 16384
    const int blocks = n_rows / ROWS;     // 512

    hipLaunchKernelGGL(lora_fused2, dim3(blocks), dim3(NT), 0, stream,
                       h, A, B, out);
}